// Round 22
// baseline (400.021 us; speedup 1.0000x reference)
//
#include <hip/hip_runtime.h>
#include <hip/hip_bf16.h>
#include <stdint.h>

#define NWIN 2048
#define NTOK 49
#define CDIM 384
#define NHEAD 12
#define HD 32
#define C3 1152
#define NN2 2401
#define MROWS 100352  // 2048*49
#define BST 52        // padded m-stride for bias/mask (16B-aligned float4 rows)

typedef __bf16 bf16x8 __attribute__((ext_vector_type(8)));
typedef float f32x4 __attribute__((ext_vector_type(4)));
typedef uint32_t u32x4 __attribute__((ext_vector_type(4)));
typedef unsigned int u32;

static __device__ __forceinline__ unsigned short f2bf(float f) {
  uint32_t u = __builtin_bit_cast(uint32_t, f);
  u += 0x7fffu + ((u >> 16) & 1u);
  return (unsigned short)(u >> 16);
}

// R13 lesson: hand asm cvt_pk wrong pack semantics; R19: library pair-conv neutral.
// Bit-twiddle composition is the verified best-measured form (R15).
static __device__ __forceinline__ u32 pk2(float a, float b) {
  return (u32)f2bf(a) | ((u32)f2bf(b) << 16);
}

static __device__ __forceinline__ void gload_lds16(const void* g, void* l) {
  __builtin_amdgcn_global_load_lds((const __attribute__((address_space(1))) void*)g,
                                   (__attribute__((address_space(3))) void*)l,
                                   16, 0, 0);
}

static __device__ __forceinline__ bf16x8 zero8() {
  u32x4 z = {0u, 0u, 0u, 0u};
  return __builtin_bit_cast(bf16x8, z);
}

// ---------------- fused mul + prep: blocks [0,2048) = A=bf16(x*stagein); [2048,2560) = prep ----
// biasF[h][n][m] (m-stride 52, 16B-aligned rows): one float4 per (nt,mt) read in attn.
__global__ void mul_prep_kernel(const float4* __restrict__ x, const float4* __restrict__ s,
                                u32x4* __restrict__ A, int n8,
                                const float* __restrict__ qkv_w, const float* __restrict__ proj_w,
                                const float* __restrict__ table, const int* __restrict__ idx,
                                unsigned short* __restrict__ wq, unsigned short* __restrict__ wp,
                                float* __restrict__ biasF) {
  const int tid = threadIdx.x;
  if (blockIdx.x < 2048) {
    int i0 = blockIdx.x * 256 + tid;
    const int stride = 2048 * 256;
    for (int t = i0; t < n8; t += stride) {
      float4 a0 = x[2 * t], a1 = x[2 * t + 1];
      float4 b0 = s[2 * t], b1 = s[2 * t + 1];
      u32x4 o;
      o[0] = pk2(a0.x * b0.x, a0.y * b0.y);
      o[1] = pk2(a0.z * b0.z, a0.w * b0.w);
      o[2] = pk2(a1.x * b1.x, a1.y * b1.y);
      o[3] = pk2(a1.z * b1.z, a1.w * b1.w);
      A[t] = o;
    }
  } else {
    const int NW1 = C3 * CDIM;          // 442368
    const int NW2 = CDIM * CDIM;        // 147456
    const int NB = NHEAD * 49 * BST;    // 30576 (valid n-rows only)
    int i = (blockIdx.x - 2048) * 256 + tid;
    const int stride = 512 * 256;
    for (int t = i; t < NW1 + NW2 + NB; t += stride) {
      if (t < NW1) {
        wq[t] = f2bf(qkv_w[t]);
      } else if (t < NW1 + NW2) {
        int j = t - NW1;
        wp[j] = f2bf(proj_w[j]);
      } else {
        int j = t - NW1 - NW2;
        int h = j / (49 * BST);
        int rem = j - h * (49 * BST);
        int n = rem / BST, m = rem - n * BST;
        float v = 0.f;
        if (m < 49) v = table[idx[n * 49 + m] * NHEAD + h];
        biasF[((size_t)h * 64 + n) * BST + m] = v;
      }
    }
  }
}

// ---------------- QKV GEMM: 8 waves x (64x64 acc), 256x128 block tile ----------------
// qkv was LDS-read-port-bound (reads:MFMA cycles ~1000:614 per block-kt). 64x64 acc halves
// reads/MFMA (0.75->0.5). LDS 48KB -> 3 blocks/CU (LDS-limited, 75% wave cap). 64 AGPR acc is
// safe WITHOUT the (,2) reg clamp (R2/R8 spills were the 128-reg clamp, not acc size):
// __launch_bounds__(512,1) = 512-reg budget. Canary: WRITE_SIZE ~226MB (spill -> revert).
__launch_bounds__(512, 1)
__global__ void qkv_gemm(const unsigned short* __restrict__ A,
                         const unsigned short* __restrict__ Bw,
                         const float* __restrict__ qkvb,
                         unsigned short* __restrict__ qo,
                         unsigned short* __restrict__ ko,
                         unsigned short* __restrict__ vo) {
  __shared__ unsigned short As[256 * 64];   // 32 KB
  __shared__ unsigned short Bs[128 * 64];   // 16 KB
  const int tid = threadIdx.x;
  const int w = tid >> 6, l = tid & 63;
  const int l15 = l & 15, lhi = l >> 4;
  // XCD swizzle: 3528 blocks = 8 XCDs x 441 (392 mt x 9 nt)
  const int wgid = (blockIdx.x & 7) * 441 + (blockIdx.x >> 3);
  const int mt = wgid / 9, nt = wgid - mt * 9;
  const int wr = w >> 1, wc = w & 1;              // 4 x 2 wave grid; wave owns 64x64
  const int srow = tid >> 3;                      // 0..63
  const int scb = (tid & 7) ^ (srow & 7);         // source col-block, XOR pre-swizzle
  const unsigned short* Ag = A + (size_t)(mt * 256 + srow) * CDIM + scb * 8;
  const unsigned short* Bg = Bw + (size_t)(nt * 128 + srow) * CDIM + scb * 8;
  unsigned short* Asl = As + srow * 64 + (tid & 7) * 8;   // linear dest (gload_lds requirement)
  unsigned short* Bsl = Bs + srow * 64 + (tid & 7) * 8;
  const f32x4 z4 = {0.f, 0.f, 0.f, 0.f};
  f32x4 acc[4][4];
#pragma unroll
  for (int m = 0; m < 4; ++m)
#pragma unroll
    for (int n = 0; n < 4; ++n) acc[m][n] = z4;
  const int xr = l15 & 7;
  for (int kt = 0; kt < 6; ++kt) {
    const unsigned short* ag = Ag + kt * 64;
    const unsigned short* bg = Bg + kt * 64;
    gload_lds16(ag, Asl);
    gload_lds16(ag + 64 * CDIM, Asl + 4096);
    gload_lds16(ag + 128 * CDIM, Asl + 8192);
    gload_lds16(ag + 192 * CDIM, Asl + 12288);
    gload_lds16(bg, Bsl);
    gload_lds16(bg + 64 * CDIM, Bsl + 4096);
    __syncthreads();
#pragma unroll
    for (int kk = 0; kk < 2; ++kk) {
      const int sl = ((kk << 2) | lhi) ^ xr;      // swizzled 8-short slot within the row
      bf16x8 af[4], bfr[4];
#pragma unroll
      for (int m = 0; m < 4; ++m)
        af[m] = *(const bf16x8*)(As + (wr * 64 + m * 16 + l15) * 64 + sl * 8);
#pragma unroll
      for (int n = 0; n < 4; ++n)
        bfr[n] = *(const bf16x8*)(Bs + (wc * 64 + n * 16 + l15) * 64 + sl * 8);
#pragma unroll
      for (int m = 0; m < 4; ++m)
#pragma unroll
        for (int n = 0; n < 4; ++n)
          acc[m][n] = __builtin_amdgcn_mfma_f32_16x16x32_bf16(af[m], bfr[n], acc[m][n], 0, 0, 0);
    }
    __syncthreads();
  }
  // epilogue: 64-col granules; six = nt*2 + wc in 0..17; which = six/6 (wave-uniform)
  const float SCALE_F = 0.17677669529663687f;
  const int six = nt * 2 + wc;
  const int which = six / 6;
  const int cbase = (six - which * 6) * 64;       // 0..320
  unsigned short* outw = (which == 0) ? qo : ((which == 1) ? ko : vo);
  const float* bptr = qkvb + which * CDIM;
  float bv4[4];
#pragma unroll
  for (int n = 0; n < 4; ++n) bv4[n] = bptr[cbase + n * 16 + l15];
#pragma unroll
  for (int m = 0; m < 4; ++m) {
    const int r0 = mt * 256 + wr * 64 + m * 16 + lhi * 4;
#pragma unroll
    for (int j = 0; j < 4; ++j) {
      unsigned short* orow = outw + (size_t)(r0 + j) * CDIM;
#pragma unroll
      for (int n = 0; n < 4; ++n) {
        float val = acc[m][n][j] + bv4[n];
        if (which == 0) val *= SCALE_F;
        orow[cbase + n * 16 + l15] = f2bf(val);
      }
    }
  }
}

// ---------------- attention: 1 block per WINDOW, 12 waves = 12 heads  [R21 known-good] --------
__launch_bounds__(768, 2)
__global__ void attn_kernel(const unsigned short* __restrict__ q,
                            const unsigned short* __restrict__ kmat,
                            const unsigned short* __restrict__ vmat,
                            const float* __restrict__ mask,
                            const float* __restrict__ biasF,
                            unsigned short* __restrict__ attnout) {
  __shared__ unsigned short vT_lds[12][32 * 72];
  __shared__ float maskLds[64 * BST];
  const int tid = threadIdx.x;
  const int w = tid >> 6, l = tid & 63;           // w = head 0..11
  const int l15 = l & 15, lhi = l >> 4;
  // XCD swizzle: 2048 = 8 x 256
  const int b = (blockIdx.x & 7) * 256 + (blockIdx.x >> 3);
  unsigned short* Vw = &vT_lds[w][0];
  const f32x4 z4 = {0.f, 0.f, 0.f, 0.f};
  const int h = w;
  const size_t rowbase = (size_t)b * NTOK * CDIM + h * HD;
  const unsigned short* qb = q + rowbase;
  const unsigned short* kb = kmat + rowbase;
  const unsigned short* vb = vmat + rowbase;
  // cooperative mask stage (row-major [n][m], padded stride 52)
  {
    const float* mb = mask + (size_t)b * NN2;
    for (int i = tid; i < NN2; i += 768) {
      const int n = i / 49, m = i - n * 49;
      maskLds[n * BST + m] = mb[i];
    }
  }
  // stage v^T into wave-private LDS (zero pad cols >=49)
  {
    const int n = l;
    unsigned short tmp[32];
    if (n < 49) {
      *(u32x4*)(&tmp[0])  = *(const u32x4*)(vb + (size_t)n * CDIM);
      *(u32x4*)(&tmp[8])  = *(const u32x4*)(vb + (size_t)n * CDIM + 8);
      *(u32x4*)(&tmp[16]) = *(const u32x4*)(vb + (size_t)n * CDIM + 16);
      *(u32x4*)(&tmp[24]) = *(const u32x4*)(vb + (size_t)n * CDIM + 24);
    } else {
#pragma unroll
      for (int d2 = 0; d2 < 32; ++d2) tmp[d2] = 0;
    }
#pragma unroll
    for (int d2 = 0; d2 < 32; ++d2) Vw[d2 * 72 + n] = tmp[d2];
  }
  // q/k fragments (hd=32 == one MFMA K)
  bf16x8 aq[4], bk[4];
#pragma unroll
  for (int t = 0; t < 4; ++t) {
    const int row = t * 16 + l15;
    if (row < 49) {
      aq[t] = *(const bf16x8*)(qb + (size_t)row * CDIM + lhi * 8);
      bk[t] = *(const bf16x8*)(kb + (size_t)row * CDIM + lhi * 8);
    } else {
      aq[t] = zero8();
      bk[t] = zero8();
    }
  }
  __syncthreads();   // maskLds ready (vT is wave-private; q/k in regs)
  const float* biasb = biasF + (size_t)h * 64 * BST;
  u32 P4[4][4][2];
#pragma unroll
  for (int nt = 0; nt < 4; ++nt) {
    f32x4 s4[4];
#pragma unroll
    for (int mt = 0; mt < 4; ++mt)
      s4[mt] = __builtin_amdgcn_mfma_f32_16x16x32_bf16(bk[mt], aq[nt], z4, 0, 0, 0);
    const int n = nt * 16 + l15;
    const int nok = (n < 49);
#pragma unroll
    for (int mt = 0; mt < 4; ++mt) {
      const int m0 = mt * 16 + lhi * 4;
      const float4 bv = *(const float4*)(biasb + (size_t)n * BST + m0);
      const float4 mv = *(const float4*)(maskLds + n * BST + m0);
      const float badd[4] = {bv.x + mv.x, bv.y + mv.y, bv.z + mv.z, bv.w + mv.w};
#pragma unroll
      for (int r = 0; r < 4; ++r) {
        float val = -1e30f;
        if (nok && (m0 + r) < 49)
          val = s4[mt][r] + badd[r];
        s4[mt][r] = val;
      }
    }
    float mx = s4[0][0];
#pragma unroll
    for (int mt = 0; mt < 4; ++mt)
#pragma unroll
      for (int r = 0; r < 4; ++r) mx = fmaxf(mx, s4[mt][r]);
    mx = fmaxf(mx, __shfl_xor(mx, 16));
    mx = fmaxf(mx, __shfl_xor(mx, 32));
    float sum = 0.f;
#pragma unroll
    for (int mt = 0; mt < 4; ++mt)
#pragma unroll
      for (int r = 0; r < 4; ++r) {
        s4[mt][r] = __expf(s4[mt][r] - mx);
        sum += s4[mt][r];
      }
    sum += __shfl_xor(sum, 16);
    sum += __shfl_xor(sum, 32);
    const float rinv = 1.0f / sum;
#pragma unroll
    for (int mt = 0; mt < 4; ++mt) {
      P4[nt][mt][0] = pk2(s4[mt][0] * rinv, s4[mt][1] * rinv);
      P4[nt][mt][1] = pk2(s4[mt][2] * rinv, s4[mt][3] * rinv);
    }
  }
  // PV: O[n][d] = P[n][m] @ V[m][d]; A-frag built in-register via shfl
  const int sA = ((l >> 4) & 1) * 32 + l15;
  const int sB = sA + 16;
  const bool hi_sel = (l & 32) != 0;
  f32x4 o[4][2];
#pragma unroll
  for (int ti = 0; ti < 4; ++ti) { o[ti][0] = z4; o[ti][1] = z4; }
#pragma unroll
  for (int kk = 0; kk < 2; ++kk) {
    bf16x8 bv0 = *(const bf16x8*)(Vw + l15 * 72 + kk * 32 + lhi * 8);
    bf16x8 bv1 = *(const bf16x8*)(Vw + (16 + l15) * 72 + kk * 32 + lhi * 8);
#pragma unroll
    for (int ti = 0; ti < 4; ++ti) {
      int x0 = __shfl((int)P4[ti][2 * kk][0], sA);
      int x1 = __shfl((int)P4[ti][2 * kk][1], sA);
      int y0 = __shfl((int)P4[ti][2 * kk + 1][0], sA);
      int y1 = __shfl((int)P4[ti][2 * kk + 1][1], sA);
      int x2 = __shfl((int)P4[ti][2 * kk][0], sB);
      int x3 = __shfl((int)P4[ti][2 * kk][1], sB);
      int y2 = __shfl((int)P4[ti][2 * kk + 1][0], sB);
      int y3 = __shfl((int)P4[ti][2 * kk + 1][1], sB);
      u32x4 f;
      f[0] = (u32)(hi_sel ? y0 : x0);
      f[1] = (u32)(hi_sel ? y1 : x1);
      f[2] = (u32)(hi_sel ? y2 : x2);
      f[3] = (u32)(hi_sel ? y3 : x3);
      bf16x8 pa = __builtin_bit_cast(bf16x8, f);
      o[ti][0] = __builtin_amdgcn_mfma_f32_16x16x32_bf16(pa, bv0, o[ti][0], 0, 0, 0);
      o[ti][1] = __builtin_amdgcn_mfma_f32_16x16x32_bf16(pa, bv1, o[ti][1], 0, 0, 0);
    }
  }
#pragma unroll
  for (int ti = 0; ti < 4; ++ti) {
#pragma unroll
    for (int r = 0; r < 4; ++r) {
      const int n = ti * 16 + lhi * 4 + r;
      if (n < 49) {
        unsigned short* orow = attnout + ((size_t)b * NTOK + n) * CDIM + h * HD;
        orow[l15] = f2bf(o[ti][0][r]);
        orow[16 + l15] = f2bf(o[ti][1][r]);
      }
    }
  }
}

// ---------------- proj GEMM: 512-thread blocks, 8 waves x (64x32 acc), f32 out  [R15] ----------
__launch_bounds__(512, 2)
__global__ void proj_gemm(const unsigned short* __restrict__ A,
                          const unsigned short* __restrict__ Bw,
                          const float* __restrict__ pb,
                          float* __restrict__ out) {
  __shared__ unsigned short As[128 * 64];
  __shared__ unsigned short Bs[128 * 64];
  const int tid = threadIdx.x;
  const int w = tid >> 6, l = tid & 63;
  const int l15 = l & 15, lhi = l >> 4;
  const int wgid = (blockIdx.x & 7) * 294 + (blockIdx.x >> 3);
  const int mt = wgid / 3, nt = wgid - mt * 3;
  const int wr = w >> 2, wc = w & 3;
  const int srow = tid >> 3;
  const int scb = (tid & 7) ^ (srow & 7);
  const unsigned short* Ag = A + (size_t)(mt * 128 + srow) * CDIM + scb * 8;
  const unsigned short* Bg = Bw + (size_t)(nt * 128 + srow) * CDIM + scb * 8;
  unsigned short* Asl = As + srow * 64 + (tid & 7) * 8;
  unsigned short* Bsl = Bs + srow * 64 + (tid & 7) * 8;
  const f32x4 z4 = {0.f, 0.f, 0.f, 0.f};
  f32x4 acc[4][2];
#pragma unroll
  for (int m = 0; m < 4; ++m)
#pragma unroll
    for (int n = 0; n < 2; ++n) acc[m][n] = z4;
  const int xr = l15 & 7;
  for (int kt = 0; kt < 6; ++kt) {
    const unsigned short* ag = Ag + kt * 64;
    const unsigned short* bg = Bg + kt * 64;
    gload_lds16(ag, Asl);
    gload_lds16(ag + 64 * CDIM, Asl + 4096);
    gload_lds16(bg, Bsl);
    gload_lds16(bg + 64 * CDIM, Bsl + 4096);
    __syncthreads();
#pragma unroll
    for (int kk = 0; kk < 2; ++kk) {
      const int sl = ((kk << 2) | lhi) ^ xr;
      bf16x8 af[4], bfr[2];
#pragma unroll
      for (int m = 0; m < 4; ++m)
        af[m] = *(const bf16x8*)(As + (wr * 64 + m * 16 + l15) * 64 + sl * 8);
#pragma unroll
      for (int n = 0; n < 2; ++n)
        bfr[n] = *(const bf16x8*)(Bs + (wc * 32 + n * 16 + l15) * 64 + sl * 8);
#pragma unroll
      for (int m = 0; m < 4; ++m)
#pragma unroll
        for (int n = 0; n < 2; ++n)
          acc[m][n] = __builtin_amdgcn_mfma_f32_16x16x32_bf16(af[m], bfr[n], acc[m][n], 0, 0, 0);
    }
    __syncthreads();
  }
#pragma unroll
  for (int m = 0; m < 4; ++m) {
    const int r0 = mt * 128 + wr * 64 + m * 16 + lhi * 4;
#pragma unroll
    for (int j = 0; j < 4; ++j) {
      float* orow = out + (size_t)(r0 + j) * CDIM;
#pragma unroll
      for (int n = 0; n < 2; ++n) {
        const int c = nt * 128 + wc * 32 + n * 16 + l15;
        orow[c] = acc[m][n][j] + pb[c];
      }
    }
  }
}

extern "C" void kernel_launch(void* const* d_in, const int* in_sizes, int n_in,
                              void* d_out, int out_size, void* d_ws, size_t ws_size,
                              hipStream_t stream) {
  const float* x       = (const float*)d_in[0];
  const float* mask    = (const float*)d_in[1];
  const float* stagein = (const float*)d_in[2];
  const float* table   = (const float*)d_in[3];
  const int*   idx     = (const int*)d_in[4];
  const float* qkv_w   = (const float*)d_in[5];
  const float* qkv_b   = (const float*)d_in[6];
  const float* proj_w  = (const float*)d_in[7];
  const float* proj_b  = (const float*)d_in[8];
  float* out = (float*)d_out;
  char* ws = (char*)d_ws;

  const size_t SZA = (size_t)MROWS * CDIM * 2;  // 77,070,336 B
  unsigned short* Abf = (unsigned short*)(ws);
  unsigned short* qb  = (unsigned short*)(ws + SZA);
  unsigned short* kb  = (unsigned short*)(ws + 2 * SZA);
  unsigned short* vb  = (unsigned short*)(ws + 3 * SZA);
  unsigned short* wq  = (unsigned short*)(ws + 4 * SZA);
  unsigned short* wp  = (unsigned short*)(ws + 4 * SZA + (size_t)C3 * CDIM * 2);
  float* biasF        = (float*)(ws + 4 * SZA + (size_t)C3 * CDIM * 2 + (size_t)CDIM * CDIM * 2);
  // biasF: [12][64][52] f32 = 159,744 B (rows n>=49 unwritten; reads guarded)
  unsigned short* attnout = Abf;  // safe alias: Abf consumed by qkv_gemm before attn writes

  mul_prep_kernel<<<dim3(2560), dim3(256), 0, stream>>>(
      (const float4*)x, (const float4*)stagein, (u32x4*)Abf, MROWS * CDIM / 8,
      qkv_w, proj_w, table, idx, wq, wp, biasF);
  qkv_gemm<<<dim3(3528), dim3(512), 0, stream>>>(Abf, wq, qkv_b, qb, kb, vb);
  attn_kernel<<<dim3(NWIN), dim3(768), 0, stream>>>(qb, kb, vb, mask, biasF, attnout);
  proj_gemm<<<dim3(784 * 3), dim3(512), 0, stream>>>(attnout, wp, proj_b, out);
}

// Round 23
// 395.103 us; speedup vs baseline: 1.0124x; 1.0124x over previous
//
#include <hip/hip_runtime.h>
#include <hip/hip_bf16.h>
#include <stdint.h>

#define NWIN 2048
#define NTOK 49
#define CDIM 384
#define NHEAD 12
#define HD 32
#define C3 1152
#define NN2 2401
#define MROWS 100352  // 2048*49
#define BST 52        // padded m-stride for bias/mask (16B-aligned float4 rows)

typedef __bf16 bf16x8 __attribute__((ext_vector_type(8)));
typedef float f32x4 __attribute__((ext_vector_type(4)));
typedef uint32_t u32x4 __attribute__((ext_vector_type(4)));
typedef unsigned int u32;

static __device__ __forceinline__ unsigned short f2bf(float f) {
  uint32_t u = __builtin_bit_cast(uint32_t, f);
  u += 0x7fffu + ((u >> 16) & 1u);
  return (unsigned short)(u >> 16);
}

// R13 lesson: hand asm cvt_pk wrong pack semantics; R19: library pair-conv neutral.
// Bit-twiddle composition is the verified best-measured form (R15).
static __device__ __forceinline__ u32 pk2(float a, float b) {
  return (u32)f2bf(a) | ((u32)f2bf(b) << 16);
}

static __device__ __forceinline__ void gload_lds16(const void* g, void* l) {
  __builtin_amdgcn_global_load_lds((const __attribute__((address_space(1))) void*)g,
                                   (__attribute__((address_space(3))) void*)l,
                                   16, 0, 0);
}

static __device__ __forceinline__ bf16x8 zero8() {
  u32x4 z = {0u, 0u, 0u, 0u};
  return __builtin_bit_cast(bf16x8, z);
}

// ---------------- fused mul + prep: blocks [0,2048) = A=bf16(x*stagein); [2048,2560) = prep ----
// biasF[h][n][m] (m-stride 52, 16B-aligned rows): one float4 per (nt,mt) read in attn.
__global__ void mul_prep_kernel(const float4* __restrict__ x, const float4* __restrict__ s,
                                u32x4* __restrict__ A, int n8,
                                const float* __restrict__ qkv_w, const float* __restrict__ proj_w,
                                const float* __restrict__ table, const int* __restrict__ idx,
                                unsigned short* __restrict__ wq, unsigned short* __restrict__ wp,
                                float* __restrict__ biasF) {
  const int tid = threadIdx.x;
  if (blockIdx.x < 2048) {
    int i0 = blockIdx.x * 256 + tid;
    const int stride = 2048 * 256;
    for (int t = i0; t < n8; t += stride) {
      float4 a0 = x[2 * t], a1 = x[2 * t + 1];
      float4 b0 = s[2 * t], b1 = s[2 * t + 1];
      u32x4 o;
      o[0] = pk2(a0.x * b0.x, a0.y * b0.y);
      o[1] = pk2(a0.z * b0.z, a0.w * b0.w);
      o[2] = pk2(a1.x * b1.x, a1.y * b1.y);
      o[3] = pk2(a1.z * b1.z, a1.w * b1.w);
      A[t] = o;
    }
  } else {
    const int NW1 = C3 * CDIM;          // 442368
    const int NW2 = CDIM * CDIM;        // 147456
    const int NB = NHEAD * 49 * BST;    // 30576 (valid n-rows only)
    int i = (blockIdx.x - 2048) * 256 + tid;
    const int stride = 512 * 256;
    for (int t = i; t < NW1 + NW2 + NB; t += stride) {
      if (t < NW1) {
        wq[t] = f2bf(qkv_w[t]);
      } else if (t < NW1 + NW2) {
        int j = t - NW1;
        wp[j] = f2bf(proj_w[j]);
      } else {
        int j = t - NW1 - NW2;
        int h = j / (49 * BST);
        int rem = j - h * (49 * BST);
        int n = rem / BST, m = rem - n * BST;
        float v = 0.f;
        if (m < 49) v = table[idx[n * 49 + m] * NHEAD + h];
        biasF[((size_t)h * 64 + n) * BST + m] = v;
      }
    }
  }
}

// ---------------- QKV GEMM: 512-thread blocks, 8 waves x (64x32 acc)  [R9/R15 known-good] ------
// All structural variants measured and rejected: R2/R8 (64-AGPR + reg clamp -> spill),
// R11 (dbuf+counted-vmcnt: occ 73->37% beat drain-removal), R17 (B-direct: scattered VMEM),
// R22 (64x64 acc/48KB LDS: occ 70->36%, MfmaUtil down). 2-phase 32KB + 70% occ = 140us floor.
__launch_bounds__(512, 2)
__global__ void qkv_gemm(const unsigned short* __restrict__ A,
                         const unsigned short* __restrict__ Bw,
                         const float* __restrict__ qkvb,
                         unsigned short* __restrict__ qo,
                         unsigned short* __restrict__ ko,
                         unsigned short* __restrict__ vo) {
  __shared__ unsigned short As[128 * 64];
  __shared__ unsigned short Bs[128 * 64];
  const int tid = threadIdx.x;
  const int w = tid >> 6, l = tid & 63;
  const int l15 = l & 15, lhi = l >> 4;
  const int wgid = (blockIdx.x & 7) * 882 + (blockIdx.x >> 3);
  const int mt = wgid / 9, nt = wgid - mt * 9;
  const int wr = w >> 2, wc = w & 3;              // 2 x 4 wave grid; wave owns 64x32
  const int srow = tid >> 3;                      // 0..63
  const int scb = (tid & 7) ^ (srow & 7);         // source col-block, XOR pre-swizzle
  const unsigned short* Ag = A + (size_t)(mt * 128 + srow) * CDIM + scb * 8;
  const unsigned short* Bg = Bw + (size_t)(nt * 128 + srow) * CDIM + scb * 8;
  unsigned short* Asl = As + srow * 64 + (tid & 7) * 8;   // linear dest (gload_lds requirement)
  unsigned short* Bsl = Bs + srow * 64 + (tid & 7) * 8;
  const f32x4 z4 = {0.f, 0.f, 0.f, 0.f};
  f32x4 acc[4][2];
#pragma unroll
  for (int m = 0; m < 4; ++m)
#pragma unroll
    for (int n = 0; n < 2; ++n) acc[m][n] = z4;
  const int xr = l15 & 7;
  for (int kt = 0; kt < 6; ++kt) {
    const unsigned short* ag = Ag + kt * 64;
    const unsigned short* bg = Bg + kt * 64;
    gload_lds16(ag, Asl);
    gload_lds16(ag + 64 * CDIM, Asl + 4096);
    gload_lds16(bg, Bsl);
    gload_lds16(bg + 64 * CDIM, Bsl + 4096);
    __syncthreads();
#pragma unroll
    for (int kk = 0; kk < 2; ++kk) {
      const int sl = ((kk << 2) | lhi) ^ xr;      // swizzled 8-short slot within the row
      bf16x8 af[4], bfr[2];
#pragma unroll
      for (int m = 0; m < 4; ++m)
        af[m] = *(const bf16x8*)(As + (wr * 64 + m * 16 + l15) * 64 + sl * 8);
#pragma unroll
      for (int n = 0; n < 2; ++n)
        bfr[n] = *(const bf16x8*)(Bs + (wc * 32 + n * 16 + l15) * 64 + sl * 8);
#pragma unroll
      for (int m = 0; m < 4; ++m)
#pragma unroll
        for (int n = 0; n < 2; ++n)
          acc[m][n] = __builtin_amdgcn_mfma_f32_16x16x32_bf16(af[m], bfr[n], acc[m][n], 0, 0, 0);
    }
    __syncthreads();
  }
  // epilogue: 32-col granules; six = nt*4 + wc in 0..35; which = six/12 (wave-uniform)
  const float SCALE_F = 0.17677669529663687f;
  const int six = nt * 4 + wc;
  const int which = six / 12;
  const int cbase = (six - which * 12) * 32;      // 0..352
  unsigned short* outw = (which == 0) ? qo : ((which == 1) ? ko : vo);
  const float* bptr = qkvb + which * CDIM;
  float bv2[2];
#pragma unroll
  for (int n = 0; n < 2; ++n) bv2[n] = bptr[cbase + n * 16 + l15];
#pragma unroll
  for (int m = 0; m < 4; ++m) {
    const int r0 = mt * 128 + wr * 64 + m * 16 + lhi * 4;
#pragma unroll
    for (int j = 0; j < 4; ++j) {
      unsigned short* orow = outw + (size_t)(r0 + j) * CDIM;
#pragma unroll
      for (int n = 0; n < 2; ++n) {
        float val = acc[m][n][j] + bv2[n];
        if (which == 0) val *= SCALE_F;
        orow[cbase + n * 16 + l15] = f2bf(val);
      }
    }
  }
}

// ---------------- attention: 1 block per WINDOW, 12 waves = 12 heads  [R21 known-good] --------
__launch_bounds__(768, 2)
__global__ void attn_kernel(const unsigned short* __restrict__ q,
                            const unsigned short* __restrict__ kmat,
                            const unsigned short* __restrict__ vmat,
                            const float* __restrict__ mask,
                            const float* __restrict__ biasF,
                            unsigned short* __restrict__ attnout) {
  __shared__ unsigned short vT_lds[12][32 * 72];
  __shared__ float maskLds[64 * BST];
  const int tid = threadIdx.x;
  const int w = tid >> 6, l = tid & 63;           // w = head 0..11
  const int l15 = l & 15, lhi = l >> 4;
  // XCD swizzle: 2048 = 8 x 256
  const int b = (blockIdx.x & 7) * 256 + (blockIdx.x >> 3);
  unsigned short* Vw = &vT_lds[w][0];
  const f32x4 z4 = {0.f, 0.f, 0.f, 0.f};
  const int h = w;
  const size_t rowbase = (size_t)b * NTOK * CDIM + h * HD;
  const unsigned short* qb = q + rowbase;
  const unsigned short* kb = kmat + rowbase;
  const unsigned short* vb = vmat + rowbase;
  // cooperative mask stage (row-major [n][m], padded stride 52)
  {
    const float* mb = mask + (size_t)b * NN2;
    for (int i = tid; i < NN2; i += 768) {
      const int n = i / 49, m = i - n * 49;
      maskLds[n * BST + m] = mb[i];
    }
  }
  // stage v^T into wave-private LDS (zero pad cols >=49)
  {
    const int n = l;
    unsigned short tmp[32];
    if (n < 49) {
      *(u32x4*)(&tmp[0])  = *(const u32x4*)(vb + (size_t)n * CDIM);
      *(u32x4*)(&tmp[8])  = *(const u32x4*)(vb + (size_t)n * CDIM + 8);
      *(u32x4*)(&tmp[16]) = *(const u32x4*)(vb + (size_t)n * CDIM + 16);
      *(u32x4*)(&tmp[24]) = *(const u32x4*)(vb + (size_t)n * CDIM + 24);
    } else {
#pragma unroll
      for (int d2 = 0; d2 < 32; ++d2) tmp[d2] = 0;
    }
#pragma unroll
    for (int d2 = 0; d2 < 32; ++d2) Vw[d2 * 72 + n] = tmp[d2];
  }
  // q/k fragments (hd=32 == one MFMA K)
  bf16x8 aq[4], bk[4];
#pragma unroll
  for (int t = 0; t < 4; ++t) {
    const int row = t * 16 + l15;
    if (row < 49) {
      aq[t] = *(const bf16x8*)(qb + (size_t)row * CDIM + lhi * 8);
      bk[t] = *(const bf16x8*)(kb + (size_t)row * CDIM + lhi * 8);
    } else {
      aq[t] = zero8();
      bk[t] = zero8();
    }
  }
  __syncthreads();   // maskLds ready (vT is wave-private; q/k in regs)
  const float* biasb = biasF + (size_t)h * 64 * BST;
  u32 P4[4][4][2];
#pragma unroll
  for (int nt = 0; nt < 4; ++nt) {
    f32x4 s4[4];
#pragma unroll
    for (int mt = 0; mt < 4; ++mt)
      s4[mt] = __builtin_amdgcn_mfma_f32_16x16x32_bf16(bk[mt], aq[nt], z4, 0, 0, 0);
    const int n = nt * 16 + l15;
    const int nok = (n < 49);
#pragma unroll
    for (int mt = 0; mt < 4; ++mt) {
      const int m0 = mt * 16 + lhi * 4;
      const float4 bv = *(const float4*)(biasb + (size_t)n * BST + m0);
      const float4 mv = *(const float4*)(maskLds + n * BST + m0);
      const float badd[4] = {bv.x + mv.x, bv.y + mv.y, bv.z + mv.z, bv.w + mv.w};
#pragma unroll
      for (int r = 0; r < 4; ++r) {
        float val = -1e30f;
        if (nok && (m0 + r) < 49)
          val = s4[mt][r] + badd[r];
        s4[mt][r] = val;
      }
    }
    float mx = s4[0][0];
#pragma unroll
    for (int mt = 0; mt < 4; ++mt)
#pragma unroll
      for (int r = 0; r < 4; ++r) mx = fmaxf(mx, s4[mt][r]);
    mx = fmaxf(mx, __shfl_xor(mx, 16));
    mx = fmaxf(mx, __shfl_xor(mx, 32));
    float sum = 0.f;
#pragma unroll
    for (int mt = 0; mt < 4; ++mt)
#pragma unroll
      for (int r = 0; r < 4; ++r) {
        s4[mt][r] = __expf(s4[mt][r] - mx);
        sum += s4[mt][r];
      }
    sum += __shfl_xor(sum, 16);
    sum += __shfl_xor(sum, 32);
    const float rinv = 1.0f / sum;
#pragma unroll
    for (int mt = 0; mt < 4; ++mt) {
      P4[nt][mt][0] = pk2(s4[mt][0] * rinv, s4[mt][1] * rinv);
      P4[nt][mt][1] = pk2(s4[mt][2] * rinv, s4[mt][3] * rinv);
    }
  }
  // PV: O[n][d] = P[n][m] @ V[m][d]; A-frag built in-register via shfl
  const int sA = ((l >> 4) & 1) * 32 + l15;
  const int sB = sA + 16;
  const bool hi_sel = (l & 32) != 0;
  f32x4 o[4][2];
#pragma unroll
  for (int ti = 0; ti < 4; ++ti) { o[ti][0] = z4; o[ti][1] = z4; }
#pragma unroll
  for (int kk = 0; kk < 2; ++kk) {
    bf16x8 bv0 = *(const bf16x8*)(Vw + l15 * 72 + kk * 32 + lhi * 8);
    bf16x8 bv1 = *(const bf16x8*)(Vw + (16 + l15) * 72 + kk * 32 + lhi * 8);
#pragma unroll
    for (int ti = 0; ti < 4; ++ti) {
      int x0 = __shfl((int)P4[ti][2 * kk][0], sA);
      int x1 = __shfl((int)P4[ti][2 * kk][1], sA);
      int y0 = __shfl((int)P4[ti][2 * kk + 1][0], sA);
      int y1 = __shfl((int)P4[ti][2 * kk + 1][1], sA);
      int x2 = __shfl((int)P4[ti][2 * kk][0], sB);
      int x3 = __shfl((int)P4[ti][2 * kk][1], sB);
      int y2 = __shfl((int)P4[ti][2 * kk + 1][0], sB);
      int y3 = __shfl((int)P4[ti][2 * kk + 1][1], sB);
      u32x4 f;
      f[0] = (u32)(hi_sel ? y0 : x0);
      f[1] = (u32)(hi_sel ? y1 : x1);
      f[2] = (u32)(hi_sel ? y2 : x2);
      f[3] = (u32)(hi_sel ? y3 : x3);
      bf16x8 pa = __builtin_bit_cast(bf16x8, f);
      o[ti][0] = __builtin_amdgcn_mfma_f32_16x16x32_bf16(pa, bv0, o[ti][0], 0, 0, 0);
      o[ti][1] = __builtin_amdgcn_mfma_f32_16x16x32_bf16(pa, bv1, o[ti][1], 0, 0, 0);
    }
  }
#pragma unroll
  for (int ti = 0; ti < 4; ++ti) {
#pragma unroll
    for (int r = 0; r < 4; ++r) {
      const int n = ti * 16 + lhi * 4 + r;
      if (n < 49) {
        unsigned short* orow = attnout + ((size_t)b * NTOK + n) * CDIM + h * HD;
        orow[l15] = f2bf(o[ti][0][r]);
        orow[16 + l15] = f2bf(o[ti][1][r]);
      }
    }
  }
}

// ---------------- proj GEMM: 512-thread blocks, 8 waves x (64x32 acc), f32 out  [R15] ----------
__launch_bounds__(512, 2)
__global__ void proj_gemm(const unsigned short* __restrict__ A,
                          const unsigned short* __restrict__ Bw,
                          const float* __restrict__ pb,
                          float* __restrict__ out) {
  __shared__ unsigned short As[128 * 64];
  __shared__ unsigned short Bs[128 * 64];
  const int tid = threadIdx.x;
  const int w = tid >> 6, l = tid & 63;
  const int l15 = l & 15, lhi = l >> 4;
  const int wgid = (blockIdx.x & 7) * 294 + (blockIdx.x >> 3);
  const int mt = wgid / 3, nt = wgid - mt * 3;
  const int wr = w >> 2, wc = w & 3;
  const int srow = tid >> 3;
  const int scb = (tid & 7) ^ (srow & 7);
  const unsigned short* Ag = A + (size_t)(mt * 128 + srow) * CDIM + scb * 8;
  const unsigned short* Bg = Bw + (size_t)(nt * 128 + srow) * CDIM + scb * 8;
  unsigned short* Asl = As + srow * 64 + (tid & 7) * 8;
  unsigned short* Bsl = Bs + srow * 64 + (tid & 7) * 8;
  const f32x4 z4 = {0.f, 0.f, 0.f, 0.f};
  f32x4 acc[4][2];
#pragma unroll
  for (int m = 0; m < 4; ++m)
#pragma unroll
    for (int n = 0; n < 2; ++n) acc[m][n] = z4;
  const int xr = l15 & 7;
  for (int kt = 0; kt < 6; ++kt) {
    const unsigned short* ag = Ag + kt * 64;
    const unsigned short* bg = Bg + kt * 64;
    gload_lds16(ag, Asl);
    gload_lds16(ag + 64 * CDIM, Asl + 4096);
    gload_lds16(bg, Bsl);
    gload_lds16(bg + 64 * CDIM, Bsl + 4096);
    __syncthreads();
#pragma unroll
    for (int kk = 0; kk < 2; ++kk) {
      const int sl = ((kk << 2) | lhi) ^ xr;
      bf16x8 af[4], bfr[2];
#pragma unroll
      for (int m = 0; m < 4; ++m)
        af[m] = *(const bf16x8*)(As + (wr * 64 + m * 16 + l15) * 64 + sl * 8);
#pragma unroll
      for (int n = 0; n < 2; ++n)
        bfr[n] = *(const bf16x8*)(Bs + (wc * 32 + n * 16 + l15) * 64 + sl * 8);
#pragma unroll
      for (int m = 0; m < 4; ++m)
#pragma unroll
        for (int n = 0; n < 2; ++n)
          acc[m][n] = __builtin_amdgcn_mfma_f32_16x16x32_bf16(af[m], bfr[n], acc[m][n], 0, 0, 0);
    }
    __syncthreads();
  }
#pragma unroll
  for (int m = 0; m < 4; ++m) {
    const int r0 = mt * 128 + wr * 64 + m * 16 + lhi * 4;
#pragma unroll
    for (int j = 0; j < 4; ++j) {
      float* orow = out + (size_t)(r0 + j) * CDIM;
#pragma unroll
      for (int n = 0; n < 2; ++n) {
        const int c = nt * 128 + wc * 32 + n * 16 + l15;
        orow[c] = acc[m][n][j] + pb[c];
      }
    }
  }
}

extern "C" void kernel_launch(void* const* d_in, const int* in_sizes, int n_in,
                              void* d_out, int out_size, void* d_ws, size_t ws_size,
                              hipStream_t stream) {
  const float* x       = (const float*)d_in[0];
  const float* mask    = (const float*)d_in[1];
  const float* stagein = (const float*)d_in[2];
  const float* table   = (const float*)d_in[3];
  const int*   idx     = (const int*)d_in[4];
  const float* qkv_w   = (const float*)d_in[5];
  const float* qkv_b   = (const float*)d_in[6];
  const float* proj_w  = (const float*)d_in[7];
  const float* proj_b  = (const float*)d_in[8];
  float* out = (float*)d_out;
  char* ws = (char*)d_ws;

  const size_t SZA = (size_t)MROWS * CDIM * 2;  // 77,070,336 B
  unsigned short* Abf = (unsigned short*)(ws);
  unsigned short* qb  = (unsigned short*)(ws + SZA);
  unsigned short* kb  = (unsigned short*)(ws + 2 * SZA);
  unsigned short* vb  = (unsigned short*)(ws + 3 * SZA);
  unsigned short* wq  = (unsigned short*)(ws + 4 * SZA);
  unsigned short* wp  = (unsigned short*)(ws + 4 * SZA + (size_t)C3 * CDIM * 2);
  float* biasF        = (float*)(ws + 4 * SZA + (size_t)C3 * CDIM * 2 + (size_t)CDIM * CDIM * 2);
  // biasF: [12][64][52] f32 = 159,744 B (rows n>=49 unwritten; reads guarded)
  unsigned short* attnout = Abf;  // safe alias: Abf consumed by qkv_gemm before attn writes

  mul_prep_kernel<<<dim3(2560), dim3(256), 0, stream>>>(
      (const float4*)x, (const float4*)stagein, (u32x4*)Abf, MROWS * CDIM / 8,
      qkv_w, proj_w, table, idx, wq, wp, biasF);
  qkv_gemm<<<dim3(784 * 9), dim3(512), 0, stream>>>(Abf, wq, qkv_b, qb, kb, vb);
  attn_kernel<<<dim3(NWIN), dim3(768), 0, stream>>>(qb, kb, vb, mask, biasF, attnout);
  proj_gemm<<<dim3(784 * 3), dim3(512), 0, stream>>>(attnout, wp, proj_b, out);
}